// Round 1
// baseline (1555.303 us; speedup 1.0000x reference)
//
#include <hip/hip_runtime.h>
#include <hip/hip_cooperative_groups.h>

namespace cgx = cooperative_groups;

static constexpr int NN  = 6144;
static constexpr int NE  = 98304;
static constexpr int NF  = 128;
static constexpr int NT  = 16;
static constexpr int MN  = 10;
static constexpr int NCG = 5;
static constexpr int NSK = 50;
static constexpr int WPR = NN / 32;      // 192 words per bitmap row
static constexpr int TPB = 512;
static constexpr int NBLK = 256;
static constexpr int RPT = NN / TPB;     // 12 rows per thread
static constexpr int PER_T = NN * MN;    // 61440

static_assert(TPB * RPT == NN, "row mapping");

// workspace layout in float elements
static constexpr size_t OFF_BM   = 0;                          // uint[NN*WPR]
static constexpr size_t OFF_RS   = OFF_BM + (size_t)NN * WPR;  // int[NN]
static constexpr size_t OFF_DEG  = OFF_RS + NN;                // int[NN]
static constexpr size_t OFF_CI   = OFF_DEG + NN;               // int[197120]
static constexpr size_t OFF_NNZ  = OFF_CI + 197120;            // int[1]+pad
static constexpr size_t OFF_SCAL = OFF_NNZ + 16;               // float[NT*4]
static constexpr size_t OFF_M    = OFF_SCAL + 80;              // float[NT*PER_T]
static constexpr size_t OFF_T    = OFF_M   + (size_t)NT * PER_T;
static constexpr size_t OFF_DT   = OFF_T   + (size_t)NT * PER_T;
static constexpr size_t OFF_CTC  = OFF_DT  + (size_t)NT * PER_T;
static constexpr size_t OFF_CDTC = OFF_CTC + (size_t)NT * PER_T;
// total ~6.3M floats ~= 25.2 MB

__global__ __launch_bounds__(TPB, 2) void tfgw_kernel(
    const float* __restrict__ x, const void* __restrict__ eiv,
    const float* __restrict__ tpl, const float* __restrict__ tf,
    const float* __restrict__ q0, const float* __restrict__ a0,
    float* __restrict__ out, float* __restrict__ W)
{
    __shared__ float sP[TPB * 11];            // column-partial scatter (pad 11: bank-conflict-free)
    __shared__ __align__(16) float sTF[MN * NF];
    __shared__ float sC2[MN * MN];
    __shared__ float sq[MN], scq[MN], sqC2[MN], sv[MN];
    __shared__ float sRed[32];
    __shared__ float sBC[4];
    __shared__ float sNSQ[MN];

    const int tid = threadIdx.x;
    const int bid = blockIdx.x;

    unsigned* BM  = (unsigned*)(W + OFF_BM);
    int* rowst    = (int*)(W + OFF_RS);
    int* degi     = (int*)(W + OFF_DEG);
    int* colix    = (int*)(W + OFF_CI);
    int* nnzc     = (int*)(W + OFF_NNZ);
    float* scal   = W + OFF_SCAL;
    float* Mw     = W + OFF_M;
    float* Tw     = W + OFF_T;
    float* dTw    = W + OFF_DT;
    float* Cw     = W + OFF_CTC;
    float* Dw     = W + OFF_CDTC;

    const float alpha = 1.f / (1.f + __expf(-a0[0]));
    const float invn  = 1.f / (float)NN;
    const float alpha2 = 2.f * alpha;

    cgx::grid_group grid = cgx::this_grid();

    // ---- one-time per-template constants (softmax(q0), C2^2 q, q^T C2) ----
    if (bid < NT && tid == 0) {
        const int t = bid;
        float qv[MN]; float qm = -1e30f;
        for (int j = 0; j < MN; ++j) { qv[j] = q0[t * MN + j]; qm = fmaxf(qm, qv[j]); }
        float qs = 0.f;
        for (int j = 0; j < MN; ++j) { qv[j] = __expf(qv[j] - qm); qs += qv[j]; }
        for (int j = 0; j < MN; ++j) { qv[j] /= qs; sq[j] = qv[j]; }
        for (int j = 0; j < MN; ++j) {
            float s2 = 0.f, s1 = 0.f;
            for (int k = 0; k < MN; ++k) {
                float cjk = tpl[t * MN * MN + j * MN + k];
                s2 += cjk * cjk * qv[k];
                s1 += tpl[t * MN * MN + k * MN + j] * qv[k];
            }
            scq[j] = s2;    // (C2^2 @ q)_j
            sqC2[j] = s1;   // (q^T C2)_j
        }
    }

    // ---- P0: zero bitmap + nnz counter; compute feature cost M ----
    for (int idx = bid * TPB + tid; idx < NN * WPR; idx += NBLK * TPB) BM[idx] = 0u;
    if (bid == 0 && tid == 0) *nnzc = 0;
    {
        const int t = bid >> 4, rb = bid & 15;   // 16 row-blocks of 384 per template
        for (int k = tid; k < MN * NF; k += TPB) sTF[k] = tf[t * MN * NF + k];
        __syncthreads();
        if (tid < MN) {
            float s = 0.f;
            for (int k = 0; k < NF; ++k) { float v = sTF[tid * NF + k]; s += v * v; }
            sNSQ[tid] = s;
        }
        __syncthreads();
        if (tid < 384) {
            const int i = rb * 384 + tid;
            const float4* x4 = (const float4*)(x + (size_t)i * NF);
            const float4* t4 = (const float4*)sTF;
            float acc[MN]; float xn = 0.f;
            #pragma unroll
            for (int j = 0; j < MN; ++j) acc[j] = 0.f;
            for (int k4 = 0; k4 < NF / 4; ++k4) {
                float4 xv = x4[k4];
                xn += xv.x * xv.x + xv.y * xv.y + xv.z * xv.z + xv.w * xv.w;
                #pragma unroll
                for (int j = 0; j < MN; ++j) {
                    float4 tv = t4[j * (NF / 4) + k4];
                    acc[j] += xv.x * tv.x + xv.y * tv.y + xv.z * tv.z + xv.w * tv.w;
                }
            }
            float* Mrow = Mw + (size_t)t * PER_T + (size_t)i * MN;
            #pragma unroll
            for (int j = 0; j < MN; ++j) Mrow[j] = xn + sNSQ[j] - 2.f * acc[j];
        }
    }
    grid.sync();

    // ---- P1: set adjacency bits (symmetrized, deduped) ----
    {
        const unsigned* uw = (const unsigned*)eiv;
        const bool is64 = (uw[1] == 0u && uw[3] == 0u && uw[5] == 0u);
        for (int e = bid * TPB + tid; e < NE; e += NBLK * TPB) {
            int s, d;
            if (is64) {
                s = (int)((const long long*)eiv)[e];
                d = (int)((const long long*)eiv)[NE + e];
            } else {
                s = ((const int*)eiv)[e];
                d = ((const int*)eiv)[NE + e];
            }
            atomicOr(&BM[(size_t)s * WPR + (d >> 5)], 1u << (d & 31));
            atomicOr(&BM[(size_t)d * WPR + (s >> 5)], 1u << (s & 31));
        }
    }
    grid.sync();

    // ---- P2: degrees + CSR (row order irrelevant) ----
    {
        const int i = bid * TPB + tid;
        if (i < NN) {
            int cnt = 0;
            for (int w = 0; w < WPR; ++w) cnt += __popc(BM[(size_t)i * WPR + w]);
            int st = atomicAdd(nnzc, cnt);
            rowst[i] = st; degi[i] = cnt;
            int p = st;
            for (int w = 0; w < WPR; ++w) {
                unsigned m = BM[(size_t)i * WPR + w];
                while (m) { int b = __ffs(m) - 1; m &= m - 1; colix[p++] = (w << 5) + b; }
            }
        }
    }
    grid.sync();

    // ================= CG loop =================
    for (int cgi = 0; cgi < NCG; ++cgi) {
        // ---- S phase: per-template block — update, grad, exp-domain Sinkhorn, dT, dots ----
        if (bid < NT) {
            const int t = bid;
            float* Mb  = Mw  + (size_t)t * PER_T;
            float* Tb  = Tw  + (size_t)t * PER_T;
            float* dTb = dTw + (size_t)t * PER_T;
            float* Cb  = Cw  + (size_t)t * PER_T;
            float* Db  = Dw  + (size_t)t * PER_T;

            if (tid == 0) {
                float tau = 0.f;
                if (cgi > 0) {
                    float sM = scal[t*4+0], sC = scal[t*4+1], sCT = scal[t*4+2], sA = scal[t*4+3];
                    float a = -2.f * alpha * sA;
                    float b = (1.f - alpha) * sM + alpha * (sC - 4.f * sCT);
                    if (a > 0.f) tau = fminf(fmaxf(-b / (2.f * a + 1e-16f), 0.f), 1.f);
                    else         tau = (a + b < 0.f) ? 1.f : 0.f;
                }
                sBC[0] = tau;
                scal[t*4+3] = 0.f;   // zero atomic accumulator for this step's D phase
            }
            for (int k = tid; k < MN * MN; k += TPB) sC2[k] = tpl[t * MN * MN + k];
            __syncthreads();
            const float tau = sBC[0];

            float E[RPT][MN];
            float uu[RPT];
            float gmax = 0.f;
            #pragma unroll
            for (int k = 0; k < RPT; ++k) {
                const int r = tid + k * TPB;
                const float cp = (float)degi[r] * invn;
                const size_t base = (size_t)r * MN;
                float Trow[MN], Crow[MN];
                if (cgi == 0) {
                    #pragma unroll
                    for (int j = 0; j < MN; ++j) {
                        Trow[j] = sq[j] * invn; Crow[j] = cp * sqC2[j];
                        Tb[base + j] = Trow[j]; Cb[base + j] = Crow[j];
                    }
                } else if (tau != 0.f) {
                    #pragma unroll
                    for (int j = 0; j < MN; ++j) {
                        Trow[j] = Tb[base + j] + tau * dTb[base + j];
                        Crow[j] = Cb[base + j] + tau * Db[base + j];
                        Tb[base + j] = Trow[j]; Cb[base + j] = Crow[j];
                    }
                } else {
                    #pragma unroll
                    for (int j = 0; j < MN; ++j) { Trow[j] = Tb[base + j]; Crow[j] = Cb[base + j]; }
                }
                #pragma unroll
                for (int j = 0; j < MN; ++j) {
                    float g = (1.f - alpha) * Mb[base + j] + alpha2 * (cp + scq[j] - 2.f * Crow[j]);
                    E[k][j] = g;
                    gmax = fmaxf(gmax, fabsf(g));
                }
            }
            // block max -> invreg
            #pragma unroll
            for (int d = 32; d; d >>= 1) gmax = fmaxf(gmax, __shfl_xor(gmax, d));
            if ((tid & 63) == 0) sRed[tid >> 6] = gmax;
            __syncthreads();
            if (tid == 0) {
                float m = sRed[0];
                for (int w = 1; w < TPB / 64; ++w) m = fmaxf(m, sRed[w]);
                sBC[1] = 1.f / (0.05f * m + 1e-8f);
            }
            __syncthreads();
            const float invreg = sBC[1];
            #pragma unroll
            for (int k = 0; k < RPT; ++k)
                #pragma unroll
                for (int j = 0; j < MN; ++j)
                    E[k][j] = __expf(-E[k][j] * invreg);

            #pragma unroll
            for (int k = 0; k < RPT; ++k) uu[k] = 1.f;

            // exp-domain Sinkhorn: |K|<=20 by construction (reg = 5% of max|grad|)
            for (int it = 0; it <= NSK; ++it) {
                float acc[MN];
                #pragma unroll
                for (int j = 0; j < MN; ++j) acc[j] = 0.f;
                #pragma unroll
                for (int k = 0; k < RPT; ++k) {
                    const float u = uu[k];
                    #pragma unroll
                    for (int j = 0; j < MN; ++j) acc[j] += E[k][j] * u;
                }
                #pragma unroll
                for (int j = 0; j < MN; ++j) sP[tid * 11 + j] = acc[j];
                __syncthreads();
                if (tid < 320) {                   // 10 cols x 32 lanes
                    const int j = tid >> 5, c = tid & 31;
                    float s = 0.f;
                    #pragma unroll
                    for (int kk = 0; kk < 16; ++kk) s += sP[(c + (kk << 5)) * 11 + j];
                    #pragma unroll
                    for (int d = 16; d; d >>= 1) s += __shfl_xor(s, d);
                    if (c == 0) sv[j] = sq[j] / s;  // v_j = q_j / S_j
                }
                __syncthreads();
                if (it == NSK) break;               // final extra column pass (g-update)
                float vv[MN];
                #pragma unroll
                for (int j = 0; j < MN; ++j) vv[j] = sv[j];
                #pragma unroll
                for (int k = 0; k < RPT; ++k) {
                    float R = 0.f;
                    #pragma unroll
                    for (int j = 0; j < MN; ++j) R += E[k][j] * vv[j];
                    uu[k] = invn * __builtin_amdgcn_rcpf(R);   // u_i = p / R_i
                }
            }

            // Tn = u E v ; dT = Tn - T ; partial line-search dots
            float vv[MN];
            #pragma unroll
            for (int j = 0; j < MN; ++j) vv[j] = sv[j];
            float sMdT = 0.f, sCdT = 0.f, sCTdT = 0.f;
            #pragma unroll
            for (int k = 0; k < RPT; ++k) {
                const int r = tid + k * TPB;
                const float cp = (float)degi[r] * invn;
                const size_t base = (size_t)r * MN;
                #pragma unroll
                for (int j = 0; j < MN; ++j) {
                    const float Tn = uu[k] * E[k][j] * vv[j];
                    const float dd = Tn - Tb[base + j];
                    dTb[base + j] = dd;
                    sMdT  += Mb[base + j] * dd;
                    sCdT  += (cp + scq[j]) * dd;
                    sCTdT += Cb[base + j] * dd;
                }
            }
            #pragma unroll
            for (int d = 32; d; d >>= 1) {
                sMdT  += __shfl_xor(sMdT, d);
                sCdT  += __shfl_xor(sCdT, d);
                sCTdT += __shfl_xor(sCTdT, d);
            }
            if ((tid & 63) == 0) {
                const int w = tid >> 6;
                sRed[w] = sMdT; sRed[8 + w] = sCdT; sRed[16 + w] = sCTdT;
            }
            __syncthreads();
            if (tid == 0) {
                float r0 = 0.f, r1 = 0.f, r2 = 0.f;
                for (int w = 0; w < TPB / 64; ++w) { r0 += sRed[w]; r1 += sRed[8 + w]; r2 += sRed[16 + w]; }
                scal[t*4+0] = r0; scal[t*4+1] = r1; scal[t*4+2] = r2;
            }
        }
        grid.sync();

        // ---- D phase: C1dTC2 = C1 @ dT @ C2 (sparse), plus sum(C1dTC2*dT) ----
        if (bid < 192) {                       // 16 templates x 12 blocks
            const int t = bid / 12;
            const int i = (bid - t * 12) * TPB + tid;
            for (int k = tid; k < MN * MN; k += TPB) sC2[k] = tpl[t * MN * MN + k];
            __syncthreads();
            const float* dTb = dTw + (size_t)t * PER_T;
            float y[MN];
            #pragma unroll
            for (int j = 0; j < MN; ++j) y[j] = 0.f;
            const int st = rowst[i], dg = degi[i];
            for (int e = st; e < st + dg; ++e) {
                const int j = colix[e];
                const float2* dr = (const float2*)(dTb + (size_t)j * MN);
                #pragma unroll
                for (int h = 0; h < 5; ++h) { float2 v2 = dr[h]; y[2*h] += v2.x; y[2*h+1] += v2.y; }
            }
            const float* dTi = dTb + (size_t)i * MN;
            float* Di = Dw + (size_t)t * PER_T + (size_t)i * MN;
            float dot = 0.f;
            #pragma unroll
            for (int c = 0; c < MN; ++c) {
                float o = 0.f;
                #pragma unroll
                for (int j = 0; j < MN; ++j) o += y[j] * sC2[j * MN + c];
                Di[c] = o;
                dot += o * dTi[c];
            }
            #pragma unroll
            for (int d = 32; d; d >>= 1) dot += __shfl_xor(dot, d);
            if ((tid & 63) == 0) sRed[tid >> 6] = dot;
            __syncthreads();
            if (tid == 0) {
                float s = 0.f;
                for (int w = 0; w < TPB / 64; ++w) s += sRed[w];
                atomicAdd(&scal[t*4+3], s);
            }
        }
        grid.sync();
    }

    // ---- F phase: final tau update + objective ----
    if (bid < NT) {
        const int t = bid;
        const float* Mb  = Mw  + (size_t)t * PER_T;
        const float* Tb  = Tw  + (size_t)t * PER_T;
        const float* dTb = dTw + (size_t)t * PER_T;
        const float* Cb  = Cw  + (size_t)t * PER_T;
        const float* Db  = Dw  + (size_t)t * PER_T;
        if (tid == 0) {
            float sM = scal[t*4+0], sC = scal[t*4+1], sCT = scal[t*4+2], sA = scal[t*4+3];
            float a = -2.f * alpha * sA;
            float b = (1.f - alpha) * sM + alpha * (sC - 4.f * sCT);
            float tau;
            if (a > 0.f) tau = fminf(fmaxf(-b / (2.f * a + 1e-16f), 0.f), 1.f);
            else         tau = (a + b < 0.f) ? 1.f : 0.f;
            sBC[0] = tau;
        }
        __syncthreads();
        const float tau = sBC[0];
        float gw = 0.f, wass = 0.f;
        #pragma unroll
        for (int k = 0; k < RPT; ++k) {
            const int r = tid + k * TPB;
            const float cp = (float)degi[r] * invn;
            const size_t base = (size_t)r * MN;
            #pragma unroll
            for (int j = 0; j < MN; ++j) {
                const float Tf = Tb[base + j] + tau * dTb[base + j];
                const float Cf = Cb[base + j] + tau * Db[base + j];
                gw   += (cp + scq[j] - 2.f * Cf) * Tf;
                wass += Mb[base + j] * Tf;
            }
        }
        #pragma unroll
        for (int d = 32; d; d >>= 1) {
            gw   += __shfl_xor(gw, d);
            wass += __shfl_xor(wass, d);
        }
        if ((tid & 63) == 0) { sRed[tid >> 6] = gw; sRed[8 + (tid >> 6)] = wass; }
        __syncthreads();
        if (tid == 0) {
            float g = 0.f, ws = 0.f;
            for (int w = 0; w < TPB / 64; ++w) { g += sRed[w]; ws += sRed[8 + w]; }
            out[t] = (1.f - alpha) * ws + alpha * g;
        }
    }
}

extern "C" void kernel_launch(void* const* d_in, const int* in_sizes, int n_in,
                              void* d_out, int out_size, void* d_ws, size_t ws_size,
                              hipStream_t stream) {
    const float* x   = (const float*)d_in[0];
    const void*  ei  = d_in[1];
    const float* tpl = (const float*)d_in[2];
    const float* tfp = (const float*)d_in[3];
    const float* q0  = (const float*)d_in[4];
    const float* a0  = (const float*)d_in[5];
    float* outp = (float*)d_out;
    float* Wp   = (float*)d_ws;
    void* args[] = { &x, &ei, &tpl, &tfp, &q0, &a0, &outp, &Wp };
    hipLaunchCooperativeKernel(reinterpret_cast<const void*>(&tfgw_kernel),
                               dim3(NBLK), dim3(TPB), args, 0, stream);
}